// Round 1
// baseline (79.294 us; speedup 1.0000x reference)
//
#include <hip/hip_runtime.h>
#include <math.h>

// Problem constants
#define NB 16
#define NC 64
#define HW_ 64
#define NL 4096            // 64*64
#define NCOUT 64
#define EPSF 1e-5f
#define LOG_EPSF -11.512925464970229f   // log(1e-5)

// Workspace layout (float offsets)
#define OFF_SMAG  0                      // [64][9] class-summed nws_mag
#define OFF_TANG  576                    // [64][9] class-summed nw_ang
#define OFF_WMM1  1152                   // [64][9] w1^2 / rowsum
#define OFF_WMA1  1728                   // [64][9] w1^2 / globalsum
#define OFF_WMM2T 2304                   // [c][o] w2^2 / rowsum(o), transposed
#define OFF_WMA2T 6400                   // [c][o] w2^2 / globalsum, transposed
#define OFF_M1    10496                  // [B][C][L]
#define OFF_A1    (10496 + NB*NC*NL)     // [B][C][L]

__global__ __launch_bounds__(256) void prep_kernel(
    const float* __restrict__ wm, const float* __restrict__ wa,
    const float* __restrict__ w1, const float* __restrict__ w2,
    float* __restrict__ ws)
{
    __shared__ float red[256];
    __shared__ float s_wm2, s_wa2, s_w12, s_w22;
    __shared__ float r1[64], r2[64];
    const int tid = threadIdx.x;

    // ---- global square-sums ----
    float p0 = 0.f, p1 = 0.f, p2 = 0.f, p3 = 0.f;
    for (int t = tid; t < 576; t += 256) {
        float v;
        v = wm[t]; p0 += v * v;
        v = wa[t]; p1 += v * v;
        v = w1[t]; p2 += v * v;
    }
    for (int t = tid; t < 4096; t += 256) { float v = w2[t]; p3 += v * v; }

    red[tid] = p0; __syncthreads();
    for (int s = 128; s > 0; s >>= 1) { if (tid < s) red[tid] += red[tid + s]; __syncthreads(); }
    if (tid == 0) s_wm2 = red[0]; __syncthreads();

    red[tid] = p1; __syncthreads();
    for (int s = 128; s > 0; s >>= 1) { if (tid < s) red[tid] += red[tid + s]; __syncthreads(); }
    if (tid == 0) s_wa2 = red[0]; __syncthreads();

    red[tid] = p2; __syncthreads();
    for (int s = 128; s > 0; s >>= 1) { if (tid < s) red[tid] += red[tid + s]; __syncthreads(); }
    if (tid == 0) s_w12 = red[0]; __syncthreads();

    red[tid] = p3; __syncthreads();
    for (int s = 128; s > 0; s >>= 1) { if (tid < s) red[tid] += red[tid + s]; __syncthreads(); }
    if (tid == 0) s_w22 = red[0]; __syncthreads();

    // ---- row sums ----
    if (tid < 64) {
        float s = 0.f;
        for (int k = 0; k < 9; ++k) { float v = w1[tid * 9 + k]; s += v * v; }
        r1[tid] = s;
        s = 0.f;
        for (int c = 0; c < 64; ++c) { float v = w2[tid * 64 + c]; s += v * v; }
        r2[tid] = s;
    }
    __syncthreads();

    // ---- per-channel boundary-class sums of nws_mag / nw_ang ----
    // fold-adjoint valid-tap sets: class 0 (i==0): ki in {0,1}; class 1: all; class 2 (i==63): ki in {1,2}
    if (tid < 64) {
        const int c = tid;
        float nm[9], na[9];
        #pragma unroll
        for (int k = 0; k < 9; ++k) {
            float v = wm[c * 9 + k];
            nm[k] = v * v / s_wm2;
            na[k] = wa[c * 9 + k] / s_wa2;
        }
        #pragma unroll
        for (int ci = 0; ci < 3; ++ci) {
            #pragma unroll
            for (int cj = 0; cj < 3; ++cj) {
                float sm = 0.f, sa = 0.f;
                #pragma unroll
                for (int ki = 0; ki < 3; ++ki) {
                    bool vi = (ci == 0) ? (ki < 2) : ((ci == 2) ? (ki > 0) : true);
                    if (!vi) continue;
                    #pragma unroll
                    for (int kj = 0; kj < 3; ++kj) {
                        bool vj = (cj == 0) ? (kj < 2) : ((cj == 2) ? (kj > 0) : true);
                        if (!vj) continue;
                        sm += nm[ki * 3 + kj];
                        sa += na[ki * 3 + kj];
                    }
                }
                ws[OFF_SMAG + c * 9 + ci * 3 + cj] = sm;
                ws[OFF_TANG + c * 9 + ci * 3 + cj] = sa;
            }
        }
    }

    // ---- wmm1 / wma1 ----
    for (int t = tid; t < 576; t += 256) {
        int c = t / 9;
        float v = w1[t]; v = v * v;
        ws[OFF_WMM1 + t] = v / r1[c];
        ws[OFF_WMA1 + t] = v / s_w12;
    }
    // ---- wmm2T / wma2T (transposed [c][o]) ----
    for (int t = tid; t < 4096; t += 256) {
        int o = t >> 6, c = t & 63;
        float v = w2[o * 64 + c]; v = v * v;
        ws[OFF_WMM2T + c * 64 + o] = v / r2[o];
        ws[OFF_WMA2T + c * 64 + o] = v / s_w22;
    }
}

// Stage A: per (b,c) plane. fm = N(i,j)*x_mag + S(c,cls); fa = x_ang*T(c,cls);
// m1 = 3x3 depthwise conv of log(fm+eps) (OOB tap -> log(eps)), weights wmm1
// a1 = 3x3 depthwise conv of fa (OOB tap -> 0), weights wma1
__global__ __launch_bounds__(256) void stageA_kernel(
    const float* __restrict__ x_mag, const float* __restrict__ x_ang,
    const float* __restrict__ ws,
    float* __restrict__ m1, float* __restrict__ a1)
{
    __shared__ float lfm[64][64];
    __shared__ float fas[64][64];
    __shared__ float smag_s[9], tang_s[9];

    const int tid = threadIdx.x;
    const int b = blockIdx.x >> 6;
    const int c = blockIdx.x & 63;

    if (tid < 9) {
        smag_s[tid] = ws[OFF_SMAG + c * 9 + tid];
        tang_s[tid] = ws[OFF_TANG + c * 9 + tid];
    }
    float wm1r[9], wa1r[9];
    #pragma unroll
    for (int k = 0; k < 9; ++k) {
        wm1r[k] = ws[OFF_WMM1 + c * 9 + k];
        wa1r[k] = ws[OFF_WMA1 + c * 9 + k];
    }
    __syncthreads();

    const int base = (b * NC + c) * NL;
    for (int t = tid; t < NL; t += 256) {
        int i = t >> 6, j = t & 63;
        int ci = (i == 0) ? 0 : ((i == 63) ? 2 : 1);
        int cj = (j == 0) ? 0 : ((j == 63) ? 2 : 1);
        float n = (float)(((ci == 1) ? 3 : 2) * ((cj == 1) ? 3 : 2));
        float fmv = fmaf(n, x_mag[base + t], smag_s[ci * 3 + cj]) + EPSF;
        lfm[i][j] = __logf(fmv);
        fas[i][j] = x_ang[base + t] * tang_s[ci * 3 + cj];
    }
    __syncthreads();

    for (int t = tid; t < NL; t += 256) {
        int i = t >> 6, j = t & 63;
        float accm = 0.f, acca = 0.f;
        #pragma unroll
        for (int ki = 0; ki < 3; ++ki) {
            int ii = i + ki - 1;
            bool okI = (unsigned)ii < 64u;
            int iic = okI ? ii : 0;
            #pragma unroll
            for (int kj = 0; kj < 3; ++kj) {
                int jj = j + kj - 1;
                bool ok = okI && ((unsigned)jj < 64u);
                int jjc = ((unsigned)jj < 64u) ? jj : 0;
                float lv = ok ? lfm[iic][jjc] : LOG_EPSF;
                float av = ok ? fas[iic][jjc] : 0.f;
                accm = fmaf(wm1r[ki * 3 + kj], lv, accm);
                acca = fmaf(wa1r[ki * 3 + kj], av, acca);
            }
        }
        m1[base + t] = accm;
        a1[base + t] = acca;
    }
}

// Stage B: per (b, 64-pixel tile): out_mag = exp(m1 . wmm2), out_ang = a1 . wma2,
// out[b,0,o,l]=mag*cos(ang), out[b,1,o,l]=mag*sin(ang)
__global__ __launch_bounds__(256) void stageB_kernel(
    const float* __restrict__ m1, const float* __restrict__ a1,
    const float* __restrict__ ws, float* __restrict__ out)
{
    __shared__ float m1s[64][64];   // [c][l]
    __shared__ float a1s[64][64];
    __shared__ float w2m[64][64];   // [c][o]
    __shared__ float w2a[64][64];

    const int tid = threadIdx.x;
    const int b = blockIdx.x >> 6;
    const int lt = (blockIdx.x & 63) * 64;

    for (int t = tid; t < 4096; t += 256) {
        int r = t >> 6, q = t & 63;
        w2m[r][q] = ws[OFF_WMM2T + t];
        w2a[r][q] = ws[OFF_WMA2T + t];
    }
    {
        const int l = tid & 63;
        const int tg = tid >> 6;
        #pragma unroll
        for (int r = 0; r < 16; ++r) {
            int c = r * 4 + tg;
            int g = (b * NC + c) * NL + lt + l;
            m1s[c][l] = m1[g];
            a1s[c][l] = a1[g];
        }
    }
    __syncthreads();

    const int l = tid & 63;
    const int og = tid >> 6;
    #pragma unroll 1
    for (int oi = 0; oi < 16; ++oi) {
        const int o = og * 16 + oi;
        float accm = 0.f, acca = 0.f;
        #pragma unroll
        for (int c = 0; c < 64; ++c) {
            accm = fmaf(m1s[c][l], w2m[c][o], accm);
            acca = fmaf(a1s[c][l], w2a[c][o], acca);
        }
        float mag = __expf(accm);
        float cs = __cosf(acca);
        float sn = __sinf(acca);
        int gi = ((b * 2) * NCOUT + o) * NL + lt + l;
        out[gi] = mag * cs;
        out[gi + NCOUT * NL] = mag * sn;
    }
}

extern "C" void kernel_launch(void* const* d_in, const int* in_sizes, int n_in,
                              void* d_out, int out_size, void* d_ws, size_t ws_size,
                              hipStream_t stream) {
    const float* x_mag = (const float*)d_in[0];
    const float* x_ang = (const float*)d_in[1];
    const float* w_mag = (const float*)d_in[2];
    const float* w_ang = (const float*)d_in[3];
    const float* w1    = (const float*)d_in[4];
    const float* w2    = (const float*)d_in[5];
    float* out = (float*)d_out;
    float* ws  = (float*)d_ws;   // needs (10496 + 2*16*64*4096)*4 ≈ 33.6 MB

    float* m1 = ws + OFF_M1;
    float* a1 = ws + OFF_A1;

    prep_kernel<<<1, 256, 0, stream>>>(w_mag, w_ang, w1, w2, ws);
    stageA_kernel<<<NB * NC, 256, 0, stream>>>(x_mag, x_ang, ws, m1, a1);
    stageB_kernel<<<NB * 64, 256, 0, stream>>>(m1, a1, ws, out);
}

// Round 2
// 57.219 us; speedup vs baseline: 1.3858x; 1.3858x over previous
//
#include <hip/hip_runtime.h>
#include <math.h>

// Problem constants
#define NB 16
#define NC 64
#define HW_ 64
#define NL 4096            // 64*64
#define NCOUT 64
#define EPSF 1e-5f
#define LOG_EPSF -11.512925464970229f   // log(1e-5)

// Workspace layout (float offsets)
#define OFF_SMAG  0                      // [64][9] class-summed nws_mag
#define OFF_TANG  576                    // [64][9] class-summed nw_ang
#define OFF_WMM1  1152                   // [64][9] w1^2 / rowsum
#define OFF_WMA1  1728                   // [64][9] w1^2 / globalsum
#define OFF_WMM2T 2304                   // [c][o] w2^2 / rowsum(o), transposed
#define OFF_WMA2T 6400                   // [c][o] w2^2 / globalsum, transposed
#define OFF_M1    10496                  // [B][C][L]
#define OFF_A1    (10496 + NB*NC*NL)     // [B][C][L]

__global__ __launch_bounds__(256) void prep_kernel(
    const float* __restrict__ wm, const float* __restrict__ wa,
    const float* __restrict__ w1, const float* __restrict__ w2,
    float* __restrict__ ws)
{
    __shared__ float red[256];
    __shared__ float s_wm2, s_wa2, s_w12, s_w22;
    __shared__ float r1[64], r2[64];
    const int tid = threadIdx.x;

    float p0 = 0.f, p1 = 0.f, p2 = 0.f, p3 = 0.f;
    for (int t = tid; t < 576; t += 256) {
        float v;
        v = wm[t]; p0 += v * v;
        v = wa[t]; p1 += v * v;
        v = w1[t]; p2 += v * v;
    }
    for (int t = tid; t < 4096; t += 256) { float v = w2[t]; p3 += v * v; }

    red[tid] = p0; __syncthreads();
    for (int s = 128; s > 0; s >>= 1) { if (tid < s) red[tid] += red[tid + s]; __syncthreads(); }
    if (tid == 0) s_wm2 = red[0]; __syncthreads();

    red[tid] = p1; __syncthreads();
    for (int s = 128; s > 0; s >>= 1) { if (tid < s) red[tid] += red[tid + s]; __syncthreads(); }
    if (tid == 0) s_wa2 = red[0]; __syncthreads();

    red[tid] = p2; __syncthreads();
    for (int s = 128; s > 0; s >>= 1) { if (tid < s) red[tid] += red[tid + s]; __syncthreads(); }
    if (tid == 0) s_w12 = red[0]; __syncthreads();

    red[tid] = p3; __syncthreads();
    for (int s = 128; s > 0; s >>= 1) { if (tid < s) red[tid] += red[tid + s]; __syncthreads(); }
    if (tid == 0) s_w22 = red[0]; __syncthreads();

    if (tid < 64) {
        float s = 0.f;
        for (int k = 0; k < 9; ++k) { float v = w1[tid * 9 + k]; s += v * v; }
        r1[tid] = s;
        s = 0.f;
        for (int c = 0; c < 64; ++c) { float v = w2[tid * 64 + c]; s += v * v; }
        r2[tid] = s;
    }
    __syncthreads();

    // per-channel boundary-class sums of nws_mag / nw_ang
    if (tid < 64) {
        const int c = tid;
        float nm[9], na[9];
        #pragma unroll
        for (int k = 0; k < 9; ++k) {
            float v = wm[c * 9 + k];
            nm[k] = v * v / s_wm2;
            na[k] = wa[c * 9 + k] / s_wa2;
        }
        #pragma unroll
        for (int ci = 0; ci < 3; ++ci) {
            #pragma unroll
            for (int cj = 0; cj < 3; ++cj) {
                float sm = 0.f, sa = 0.f;
                #pragma unroll
                for (int ki = 0; ki < 3; ++ki) {
                    bool vi = (ci == 0) ? (ki < 2) : ((ci == 2) ? (ki > 0) : true);
                    if (!vi) continue;
                    #pragma unroll
                    for (int kj = 0; kj < 3; ++kj) {
                        bool vj = (cj == 0) ? (kj < 2) : ((cj == 2) ? (kj > 0) : true);
                        if (!vj) continue;
                        sm += nm[ki * 3 + kj];
                        sa += na[ki * 3 + kj];
                    }
                }
                ws[OFF_SMAG + c * 9 + ci * 3 + cj] = sm;
                ws[OFF_TANG + c * 9 + ci * 3 + cj] = sa;
            }
        }
    }

    for (int t = tid; t < 576; t += 256) {
        int c = t / 9;
        float v = w1[t]; v = v * v;
        ws[OFF_WMM1 + t] = v / r1[c];
        ws[OFF_WMA1 + t] = v / s_w12;
    }
    for (int t = tid; t < 4096; t += 256) {
        int o = t >> 6, c = t & 63;
        float v = w2[o * 64 + c]; v = v * v;
        ws[OFF_WMM2T + c * 64 + o] = v / r2[o];
        ws[OFF_WMA2T + c * 64 + o] = v / s_w22;
    }
}

// ---------------- Stage A ----------------
// Per (b,c) plane: fm = N(i,j)*x_mag + S(c,cls); fa = x_ang*T(c,cls)
// m1 = 3x3 conv of log(fm+eps) (OOB tap -> log(eps)), weights wmm1
// a1 = 3x3 conv of fa (OOB tap -> 0), weights wma1
// Sentinel-padded LDS plane: rows -1..64, cols -4..67 (so all f4 loads are in-bounds)
#define PW 72
#define PH 66

__global__ __launch_bounds__(256) void stageA_kernel(
    const float* __restrict__ x_mag, const float* __restrict__ x_ang,
    const float* __restrict__ ws,
    float* __restrict__ m1, float* __restrict__ a1)
{
    __shared__ float lfm[PH][PW];
    __shared__ float fas[PH][PW];
    __shared__ float smag_s[9], tang_s[9];

    const int tid = threadIdx.x;
    const int b = blockIdx.x >> 6;
    const int c = blockIdx.x & 63;

    if (tid < 9) {
        smag_s[tid] = ws[OFF_SMAG + c * 9 + tid];
        tang_s[tid] = ws[OFF_TANG + c * 9 + tid];
    }
    float wm1r[9], wa1r[9];
    #pragma unroll
    for (int k = 0; k < 9; ++k) {
        wm1r[k] = ws[OFF_WMM1 + c * 9 + k];
        wa1r[k] = ws[OFF_WMA1 + c * 9 + k];
    }

    // sentinel fill (PH*PW/4 = 1188 float4 per array)
    {
        float4 sm4; sm4.x = sm4.y = sm4.z = sm4.w = LOG_EPSF;
        float4 z4;  z4.x = z4.y = z4.z = z4.w = 0.f;
        float4* pm = (float4*)&lfm[0][0];
        float4* pa = (float4*)&fas[0][0];
        for (int t = tid; t < (PH * PW) / 4; t += 256) { pm[t] = sm4; pa[t] = z4; }
    }
    __syncthreads();

    const int base = (b * NC + c) * NL;
    // interior fill: 4 consecutive pixels per iteration (row-aligned since 64%4==0)
    for (int g = tid; g < NL / 4; g += 256) {
        int p0 = g * 4;
        int i = p0 >> 6, j = p0 & 63;
        int ci = (i == 0) ? 0 : ((i == 63) ? 2 : 1);
        float n_i = (ci == 1) ? 3.f : 2.f;
        float smC = smag_s[ci * 3 + 1], taC = tang_s[ci * 3 + 1];
        float sm[4] = { smC, smC, smC, smC };
        float ta[4] = { taC, taC, taC, taC };
        float nn[4] = { 3.f * n_i, 3.f * n_i, 3.f * n_i, 3.f * n_i };
        if (j == 0)  { sm[0] = smag_s[ci * 3 + 0]; ta[0] = tang_s[ci * 3 + 0]; nn[0] = 2.f * n_i; }
        if (j == 60) { sm[3] = smag_s[ci * 3 + 2]; ta[3] = tang_s[ci * 3 + 2]; nn[3] = 2.f * n_i; }
        float4 xm = ((const float4*)(x_mag + base))[g];
        float4 xa = ((const float4*)(x_ang + base))[g];
        float4 lo, ao;
        lo.x = __logf(fmaf(nn[0], xm.x, sm[0]) + EPSF);
        lo.y = __logf(fmaf(nn[1], xm.y, sm[1]) + EPSF);
        lo.z = __logf(fmaf(nn[2], xm.z, sm[2]) + EPSF);
        lo.w = __logf(fmaf(nn[3], xm.w, sm[3]) + EPSF);
        ao.x = xa.x * ta[0]; ao.y = xa.y * ta[1]; ao.z = xa.z * ta[2]; ao.w = xa.w * ta[3];
        *(float4*)&lfm[i + 1][j + 4] = lo;
        *(float4*)&fas[i + 1][j + 4] = ao;
    }
    __syncthreads();

    // conv: each thread owns a 4x4 tile (rows i0..i0+3, cols j0..j0+3)
    const int i0 = (tid >> 4) * 4;
    const int j0 = (tid & 15) * 4;

    float4 accm[4], acca[4];
    #pragma unroll
    for (int li = 0; li < 4; ++li) {
        accm[li].x = accm[li].y = accm[li].z = accm[li].w = 0.f;
        acca[li].x = acca[li].y = acca[li].z = acca[li].w = 0.f;
    }

    #pragma unroll
    for (int r = 0; r < 6; ++r) {
        const int row = i0 + r;   // LDS row = (i0 - 1 + r) + 1
        float4 Lm = *(const float4*)&lfm[row][j0];
        float4 Cm = *(const float4*)&lfm[row][j0 + 4];
        float4 Rm = *(const float4*)&lfm[row][j0 + 8];
        float4 La = *(const float4*)&fas[row][j0];
        float4 Ca = *(const float4*)&fas[row][j0 + 4];
        float4 Ra = *(const float4*)&fas[row][j0 + 8];
        float slm[4] = { Lm.w, Cm.x, Cm.y, Cm.z };
        float srm[4] = { Cm.y, Cm.z, Cm.w, Rm.x };
        float scm[4] = { Cm.x, Cm.y, Cm.z, Cm.w };
        float sla[4] = { La.w, Ca.x, Ca.y, Ca.z };
        float sra[4] = { Ca.y, Ca.z, Ca.w, Ra.x };
        float sca[4] = { Ca.x, Ca.y, Ca.z, Ca.w };
        #pragma unroll
        for (int ki = 0; ki < 3; ++ki) {
            const int li = r - ki;
            if (li < 0 || li > 3) continue;   // compile-time pruned
            float wA = wm1r[ki * 3 + 0], wB = wm1r[ki * 3 + 1], wC = wm1r[ki * 3 + 2];
            float vA = wa1r[ki * 3 + 0], vB = wa1r[ki * 3 + 1], vC = wa1r[ki * 3 + 2];
            accm[li].x = fmaf(wA, slm[0], fmaf(wB, scm[0], fmaf(wC, srm[0], accm[li].x)));
            accm[li].y = fmaf(wA, slm[1], fmaf(wB, scm[1], fmaf(wC, srm[1], accm[li].y)));
            accm[li].z = fmaf(wA, slm[2], fmaf(wB, scm[2], fmaf(wC, srm[2], accm[li].z)));
            accm[li].w = fmaf(wA, slm[3], fmaf(wB, scm[3], fmaf(wC, srm[3], accm[li].w)));
            acca[li].x = fmaf(vA, sla[0], fmaf(vB, sca[0], fmaf(vC, sra[0], acca[li].x)));
            acca[li].y = fmaf(vA, sla[1], fmaf(vB, sca[1], fmaf(vC, sra[1], acca[li].y)));
            acca[li].z = fmaf(vA, sla[2], fmaf(vB, sca[2], fmaf(vC, sra[2], acca[li].z)));
            acca[li].w = fmaf(vA, sla[3], fmaf(vB, sca[3], fmaf(vC, sra[3], acca[li].w)));
        }
    }

    #pragma unroll
    for (int li = 0; li < 4; ++li) {
        *(float4*)&m1[base + (i0 + li) * 64 + j0] = accm[li];
        *(float4*)&a1[base + (i0 + li) * 64 + j0] = acca[li];
    }
}

// ---------------- Stage B ----------------
// out_mag = exp(m1 . wmm2), out_ang = a1 . wma2 over c (64-deep), then cos/sin.
// m1/a1 read directly from global (block-private tiles, f4). Only w2 in LDS.
#define W2P 68   // padded row so the 4 distinct o-groups hit disjoint bank groups

__global__ __launch_bounds__(256) void stageB_kernel(
    const float* __restrict__ m1, const float* __restrict__ a1,
    const float* __restrict__ ws, float* __restrict__ out)
{
    __shared__ float w2m[64][W2P];
    __shared__ float w2a[64][W2P];

    const int tid = threadIdx.x;
    const int b = blockIdx.x >> 6;
    const int lt = (blockIdx.x & 63) * 64;

    for (int t = tid; t < 1024; t += 256) {
        int c = t >> 4, o4 = (t & 15) * 4;
        *(float4*)&w2m[c][o4] = ((const float4*)(ws + OFF_WMM2T))[t];
        *(float4*)&w2a[c][o4] = ((const float4*)(ws + OFF_WMA2T))[t];
    }
    __syncthreads();

    const int l0 = (tid & 15) * 4;
    const int o0 = (tid >> 4) * 4;

    float4 accm[4], acca[4];   // [oi] over the 4-l vector
    #pragma unroll
    for (int oi = 0; oi < 4; ++oi) {
        accm[oi].x = accm[oi].y = accm[oi].z = accm[oi].w = 0.f;
        acca[oi].x = acca[oi].y = acca[oi].z = acca[oi].w = 0.f;
    }

    const float* m1p = m1 + (size_t)b * NC * NL + lt + l0;
    const float* a1p = a1 + (size_t)b * NC * NL + lt + l0;

    #pragma unroll 4
    for (int c = 0; c < 64; ++c) {
        float4 mv = *(const float4*)(m1p + c * NL);
        float4 av = *(const float4*)(a1p + c * NL);
        float4 wm = *(const float4*)&w2m[c][o0];
        float4 wa = *(const float4*)&w2a[c][o0];
        accm[0].x = fmaf(mv.x, wm.x, accm[0].x); accm[0].y = fmaf(mv.y, wm.x, accm[0].y);
        accm[0].z = fmaf(mv.z, wm.x, accm[0].z); accm[0].w = fmaf(mv.w, wm.x, accm[0].w);
        accm[1].x = fmaf(mv.x, wm.y, accm[1].x); accm[1].y = fmaf(mv.y, wm.y, accm[1].y);
        accm[1].z = fmaf(mv.z, wm.y, accm[1].z); accm[1].w = fmaf(mv.w, wm.y, accm[1].w);
        accm[2].x = fmaf(mv.x, wm.z, accm[2].x); accm[2].y = fmaf(mv.y, wm.z, accm[2].y);
        accm[2].z = fmaf(mv.z, wm.z, accm[2].z); accm[2].w = fmaf(mv.w, wm.z, accm[2].w);
        accm[3].x = fmaf(mv.x, wm.w, accm[3].x); accm[3].y = fmaf(mv.y, wm.w, accm[3].y);
        accm[3].z = fmaf(mv.z, wm.w, accm[3].z); accm[3].w = fmaf(mv.w, wm.w, accm[3].w);
        acca[0].x = fmaf(av.x, wa.x, acca[0].x); acca[0].y = fmaf(av.y, wa.x, acca[0].y);
        acca[0].z = fmaf(av.z, wa.x, acca[0].z); acca[0].w = fmaf(av.w, wa.x, acca[0].w);
        acca[1].x = fmaf(av.x, wa.y, acca[1].x); acca[1].y = fmaf(av.y, wa.y, acca[1].y);
        acca[1].z = fmaf(av.z, wa.y, acca[1].z); acca[1].w = fmaf(av.w, wa.y, acca[1].w);
        acca[2].x = fmaf(av.x, wa.z, acca[2].x); acca[2].y = fmaf(av.y, wa.z, acca[2].y);
        acca[2].z = fmaf(av.z, wa.z, acca[2].z); acca[2].w = fmaf(av.w, wa.z, acca[2].w);
        acca[3].x = fmaf(av.x, wa.w, acca[3].x); acca[3].y = fmaf(av.y, wa.w, acca[3].y);
        acca[3].z = fmaf(av.z, wa.w, acca[3].z); acca[3].w = fmaf(av.w, wa.w, acca[3].w);
    }

    #pragma unroll
    for (int oi = 0; oi < 4; ++oi) {
        const int o = o0 + oi;
        float4 mg, oc, os;
        mg.x = __expf(accm[oi].x); mg.y = __expf(accm[oi].y);
        mg.z = __expf(accm[oi].z); mg.w = __expf(accm[oi].w);
        oc.x = mg.x * __cosf(acca[oi].x); os.x = mg.x * __sinf(acca[oi].x);
        oc.y = mg.y * __cosf(acca[oi].y); os.y = mg.y * __sinf(acca[oi].y);
        oc.z = mg.z * __cosf(acca[oi].z); os.z = mg.z * __sinf(acca[oi].z);
        oc.w = mg.w * __cosf(acca[oi].w); os.w = mg.w * __sinf(acca[oi].w);
        size_t gi = ((size_t)(b * 2) * NCOUT + o) * NL + lt + l0;
        *(float4*)&out[gi] = oc;
        *(float4*)&out[gi + (size_t)NCOUT * NL] = os;
    }
}

extern "C" void kernel_launch(void* const* d_in, const int* in_sizes, int n_in,
                              void* d_out, int out_size, void* d_ws, size_t ws_size,
                              hipStream_t stream) {
    const float* x_mag = (const float*)d_in[0];
    const float* x_ang = (const float*)d_in[1];
    const float* w_mag = (const float*)d_in[2];
    const float* w_ang = (const float*)d_in[3];
    const float* w1    = (const float*)d_in[4];
    const float* w2    = (const float*)d_in[5];
    float* out = (float*)d_out;
    float* ws  = (float*)d_ws;

    float* m1 = ws + OFF_M1;
    float* a1 = ws + OFF_A1;

    prep_kernel<<<1, 256, 0, stream>>>(w_mag, w_ang, w1, w2, ws);
    stageA_kernel<<<NB * NC, 256, 0, stream>>>(x_mag, x_ang, ws, m1, a1);
    stageB_kernel<<<NB * 64, 256, 0, stream>>>(m1, a1, ws, out);
}

// Round 3
// 45.248 us; speedup vs baseline: 1.7524x; 1.2646x over previous
//
#include <hip/hip_runtime.h>
#include <math.h>

// Problem constants
#define NB 16
#define NC 64
#define NL 4096            // 64*64
#define NCOUT 64
#define EPSF 1e-5f
#define LOG_EPSF -11.512925464970229f   // log(1e-5)

// Workspace layout (float offsets): only the m1/a1 intermediates now
#define OFF_M1 0
#define OFF_A1 (NB*NC*NL)

// ---------------- Stage A ----------------
// Per (b,c) plane. Weight prep (global sums + per-channel class sums) is done
// redundantly per block, eliminating the serial prep kernel.
// fm = N(i,j)*x_mag + S(c,cls); fa = x_ang*T(c,cls)
// m1 = 3x3 conv of log(fm+eps) (OOB tap -> log(eps)), weights w1^2/rowsum
// a1 = 3x3 conv of fa (OOB tap -> 0), weights w1^2/globalsum
#define PW 72
#define PH 66

__global__ __launch_bounds__(256) void stageA_kernel(
    const float* __restrict__ x_mag, const float* __restrict__ x_ang,
    const float* __restrict__ wm, const float* __restrict__ wa,
    const float* __restrict__ w1,
    float* __restrict__ m1, float* __restrict__ a1)
{
    __shared__ float lfm[PH][PW];
    __shared__ float fas[PH][PW];
    __shared__ float smag_s[9], tang_s[9];
    __shared__ float red[3][4];

    const int tid = threadIdx.x;
    const int lane = tid & 63;
    const int wv = tid >> 6;
    const int b = blockIdx.x >> 6;
    const int c = blockIdx.x & 63;
    const int base = (b * NC + c) * NL;

    // 1) issue interior global loads EARLY (latency hides under weight prep)
    float4 xm[4], xa[4];
    #pragma unroll
    for (int k = 0; k < 4; ++k) {
        xm[k] = ((const float4*)(x_mag + base))[tid + k * 256];
        xa[k] = ((const float4*)(x_ang + base))[tid + k * 256];
    }

    // 2) global weight square-sums (576 elements each; redundant per block)
    float p0 = 0.f, p1 = 0.f, p2 = 0.f;
    {
        float v;
        v = wm[tid];       p0 += v * v;
        v = wm[tid + 256]; p0 += v * v;
        v = wa[tid];       p1 += v * v;
        v = wa[tid + 256]; p1 += v * v;
        v = w1[tid];       p2 += v * v;
        v = w1[tid + 256]; p2 += v * v;
        if (tid < 64) {
            v = wm[tid + 512]; p0 += v * v;
            v = wa[tid + 512]; p1 += v * v;
            v = w1[tid + 512]; p2 += v * v;
        }
    }
    #pragma unroll
    for (int s = 32; s; s >>= 1) {
        p0 += __shfl_down(p0, s);
        p1 += __shfl_down(p1, s);
        p2 += __shfl_down(p2, s);
    }
    if (lane == 0) { red[0][wv] = p0; red[1][wv] = p1; red[2][wv] = p2; }
    __syncthreads();
    const float s_wm2 = red[0][0] + red[0][1] + red[0][2] + red[0][3];
    const float s_wa2 = red[1][0] + red[1][1] + red[1][2] + red[1][3];
    const float s_w12 = red[2][0] + red[2][1] + red[2][2] + red[2][3];

    // 3) per-channel conv weights (broadcast loads, per-thread registers)
    float wm1r[9], wa1r[9];
    float r1c = 0.f;
    #pragma unroll
    for (int k = 0; k < 9; ++k) { float v = w1[c * 9 + k]; wm1r[k] = v * v; r1c += v * v; }
    {
        float inv_r = 1.f / r1c, inv_s = 1.f / s_w12;
        #pragma unroll
        for (int k = 0; k < 9; ++k) { wa1r[k] = wm1r[k] * inv_s; wm1r[k] *= inv_r; }
    }

    // 4) per-channel boundary-class sums (threads 0..8, one class each)
    if (tid < 9) {
        const int ci = tid / 3, cj = tid % 3;
        float sm = 0.f, sa = 0.f;
        #pragma unroll
        for (int ki = 0; ki < 3; ++ki) {
            bool vi = (ci == 0) ? (ki < 2) : ((ci == 2) ? (ki > 0) : true);
            if (!vi) continue;
            #pragma unroll
            for (int kj = 0; kj < 3; ++kj) {
                bool vj = (cj == 0) ? (kj < 2) : ((cj == 2) ? (kj > 0) : true);
                if (!vj) continue;
                float vm_ = wm[c * 9 + ki * 3 + kj];
                sm += vm_ * vm_;
                sa += wa[c * 9 + ki * 3 + kj];
            }
        }
        smag_s[tid] = sm / s_wm2;
        tang_s[tid] = sa / s_wa2;
    }

    // 5) border-only sentinel fill (656 cells per array, not the whole plane)
    {
        float4 sm4; sm4.x = sm4.y = sm4.z = sm4.w = LOG_EPSF;
        float4 z4;  z4.x = z4.y = z4.z = z4.w = 0.f;
        if (tid < 36) {
            int row = (tid >= 18) ? 65 : 0;
            int col4 = (tid % 18) * 4;
            *(float4*)&lfm[row][col4] = sm4;
            *(float4*)&fas[row][col4] = z4;
        } else if (tid < 164) {
            int s = tid - 36;
            int row = 1 + (s >> 1);
            int col4 = (s & 1) ? 68 : 0;
            *(float4*)&lfm[row][col4] = sm4;
            *(float4*)&fas[row][col4] = z4;
        }
    }
    __syncthreads();

    // 6) interior compute from prefetched registers
    #pragma unroll
    for (int k = 0; k < 4; ++k) {
        int g = tid + k * 256;
        int i = g >> 4, j = (g & 15) * 4;
        int ci = (i == 0) ? 0 : ((i == 63) ? 2 : 1);
        float n_i = (ci == 1) ? 3.f : 2.f;
        float smC = smag_s[ci * 3 + 1], taC = tang_s[ci * 3 + 1];
        float sm[4] = { smC, smC, smC, smC };
        float ta[4] = { taC, taC, taC, taC };
        float nn[4] = { 3.f * n_i, 3.f * n_i, 3.f * n_i, 3.f * n_i };
        if (j == 0)  { sm[0] = smag_s[ci * 3 + 0]; ta[0] = tang_s[ci * 3 + 0]; nn[0] = 2.f * n_i; }
        if (j == 60) { sm[3] = smag_s[ci * 3 + 2]; ta[3] = tang_s[ci * 3 + 2]; nn[3] = 2.f * n_i; }
        float4 lo, ao;
        lo.x = __logf(fmaf(nn[0], xm[k].x, sm[0]) + EPSF);
        lo.y = __logf(fmaf(nn[1], xm[k].y, sm[1]) + EPSF);
        lo.z = __logf(fmaf(nn[2], xm[k].z, sm[2]) + EPSF);
        lo.w = __logf(fmaf(nn[3], xm[k].w, sm[3]) + EPSF);
        ao.x = xa[k].x * ta[0]; ao.y = xa[k].y * ta[1];
        ao.z = xa[k].z * ta[2]; ao.w = xa[k].w * ta[3];
        *(float4*)&lfm[i + 1][j + 4] = lo;
        *(float4*)&fas[i + 1][j + 4] = ao;
    }
    __syncthreads();

    // 7) conv: each thread owns a 4x4 tile
    const int i0 = (tid >> 4) * 4;
    const int j0 = (tid & 15) * 4;

    float4 accm[4], acca[4];
    #pragma unroll
    for (int li = 0; li < 4; ++li) {
        accm[li].x = accm[li].y = accm[li].z = accm[li].w = 0.f;
        acca[li].x = acca[li].y = acca[li].z = acca[li].w = 0.f;
    }

    #pragma unroll
    for (int r = 0; r < 6; ++r) {
        const int row = i0 + r;
        float4 Lm = *(const float4*)&lfm[row][j0];
        float4 Cm = *(const float4*)&lfm[row][j0 + 4];
        float4 Rm = *(const float4*)&lfm[row][j0 + 8];
        float4 La = *(const float4*)&fas[row][j0];
        float4 Ca = *(const float4*)&fas[row][j0 + 4];
        float4 Ra = *(const float4*)&fas[row][j0 + 8];
        float slm[4] = { Lm.w, Cm.x, Cm.y, Cm.z };
        float srm[4] = { Cm.y, Cm.z, Cm.w, Rm.x };
        float scm[4] = { Cm.x, Cm.y, Cm.z, Cm.w };
        float sla[4] = { La.w, Ca.x, Ca.y, Ca.z };
        float sra[4] = { Ca.y, Ca.z, Ca.w, Ra.x };
        float sca[4] = { Ca.x, Ca.y, Ca.z, Ca.w };
        #pragma unroll
        for (int ki = 0; ki < 3; ++ki) {
            const int li = r - ki;
            if (li < 0 || li > 3) continue;
            float wA = wm1r[ki * 3 + 0], wB = wm1r[ki * 3 + 1], wC = wm1r[ki * 3 + 2];
            float vA = wa1r[ki * 3 + 0], vB = wa1r[ki * 3 + 1], vC = wa1r[ki * 3 + 2];
            accm[li].x = fmaf(wA, slm[0], fmaf(wB, scm[0], fmaf(wC, srm[0], accm[li].x)));
            accm[li].y = fmaf(wA, slm[1], fmaf(wB, scm[1], fmaf(wC, srm[1], accm[li].y)));
            accm[li].z = fmaf(wA, slm[2], fmaf(wB, scm[2], fmaf(wC, srm[2], accm[li].z)));
            accm[li].w = fmaf(wA, slm[3], fmaf(wB, scm[3], fmaf(wC, srm[3], accm[li].w)));
            acca[li].x = fmaf(vA, sla[0], fmaf(vB, sca[0], fmaf(vC, sra[0], acca[li].x)));
            acca[li].y = fmaf(vA, sla[1], fmaf(vB, sca[1], fmaf(vC, sra[1], acca[li].y)));
            acca[li].z = fmaf(vA, sla[2], fmaf(vB, sca[2], fmaf(vC, sra[2], acca[li].z)));
            acca[li].w = fmaf(vA, sla[3], fmaf(vB, sca[3], fmaf(vC, sra[3], acca[li].w)));
        }
    }

    #pragma unroll
    for (int li = 0; li < 4; ++li) {
        *(float4*)&m1[base + (i0 + li) * 64 + j0] = accm[li];
        *(float4*)&a1[base + (i0 + li) * 64 + j0] = acca[li];
    }
}

// ---------------- Stage B ----------------
// Builds its own normalized transposed w2 tables in LDS (no prep kernel),
// then out_mag = exp(m1 . wmm2), out_ang = a1 . wma2, cos/sin epilogue.
#define W2P 68

#define FMA_STEP(MV, AV, WM, WA)                                                      \
    accm[0].x = fmaf(MV.x, WM.x, accm[0].x); accm[0].y = fmaf(MV.y, WM.x, accm[0].y); \
    accm[0].z = fmaf(MV.z, WM.x, accm[0].z); accm[0].w = fmaf(MV.w, WM.x, accm[0].w); \
    accm[1].x = fmaf(MV.x, WM.y, accm[1].x); accm[1].y = fmaf(MV.y, WM.y, accm[1].y); \
    accm[1].z = fmaf(MV.z, WM.y, accm[1].z); accm[1].w = fmaf(MV.w, WM.y, accm[1].w); \
    accm[2].x = fmaf(MV.x, WM.z, accm[2].x); accm[2].y = fmaf(MV.y, WM.z, accm[2].y); \
    accm[2].z = fmaf(MV.z, WM.z, accm[2].z); accm[2].w = fmaf(MV.w, WM.z, accm[2].w); \
    accm[3].x = fmaf(MV.x, WM.w, accm[3].x); accm[3].y = fmaf(MV.y, WM.w, accm[3].y); \
    accm[3].z = fmaf(MV.z, WM.w, accm[3].z); accm[3].w = fmaf(MV.w, WM.w, accm[3].w); \
    acca[0].x = fmaf(AV.x, WA.x, acca[0].x); acca[0].y = fmaf(AV.y, WA.x, acca[0].y); \
    acca[0].z = fmaf(AV.z, WA.x, acca[0].z); acca[0].w = fmaf(AV.w, WA.x, acca[0].w); \
    acca[1].x = fmaf(AV.x, WA.y, acca[1].x); acca[1].y = fmaf(AV.y, WA.y, acca[1].y); \
    acca[1].z = fmaf(AV.z, WA.y, acca[1].z); acca[1].w = fmaf(AV.w, WA.y, acca[1].w); \
    acca[2].x = fmaf(AV.x, WA.z, acca[2].x); acca[2].y = fmaf(AV.y, WA.z, acca[2].y); \
    acca[2].z = fmaf(AV.z, WA.z, acca[2].z); acca[2].w = fmaf(AV.w, WA.z, acca[2].w); \
    acca[3].x = fmaf(AV.x, WA.w, acca[3].x); acca[3].y = fmaf(AV.y, WA.w, acca[3].y); \
    acca[3].z = fmaf(AV.z, WA.w, acca[3].z); acca[3].w = fmaf(AV.w, WA.w, acca[3].w);

__global__ __launch_bounds__(256) void stageB_kernel(
    const float* __restrict__ m1, const float* __restrict__ a1,
    const float* __restrict__ w2, float* __restrict__ out)
{
    __shared__ float w2m[64][W2P];
    __shared__ float w2a[64][W2P];
    __shared__ float redB[4];

    const int tid = threadIdx.x;
    const int lane = tid & 63;
    const int wv = tid >> 6;
    const int b = blockIdx.x >> 6;
    const int lt = (blockIdx.x & 63) * 64;

    // per-block w2 prep: load 4 f4 chunks, rowsum via 16-lane shfl groups,
    // global sum via block reduce, write normalized transpose into LDS
    float4 v[4];
    float rpart[4];
    float s22p = 0.f;
    #pragma unroll
    for (int k = 0; k < 4; ++k) {
        int q = tid + k * 256;
        v[k] = ((const float4*)w2)[q];
        float d = fmaf(v[k].x, v[k].x, fmaf(v[k].y, v[k].y, fmaf(v[k].z, v[k].z, v[k].w * v[k].w)));
        rpart[k] = d;
        s22p += d;
    }
    #pragma unroll
    for (int k = 0; k < 4; ++k) {
        float r = rpart[k];
        r += __shfl_xor(r, 1);
        r += __shfl_xor(r, 2);
        r += __shfl_xor(r, 4);
        r += __shfl_xor(r, 8);
        rpart[k] = r;   // = rowsum r2[o] for this chunk's o, broadcast in group
    }
    float s = s22p;
    #pragma unroll
    for (int d = 32; d; d >>= 1) s += __shfl_down(s, d);
    if (lane == 0) redB[wv] = s;
    __syncthreads();
    const float inv_s22 = 1.f / (redB[0] + redB[1] + redB[2] + redB[3]);

    #pragma unroll
    for (int k = 0; k < 4; ++k) {
        int q = tid + k * 256;
        int o = q >> 4, c4 = (q & 15) * 4;
        float inv_r = 1.f / rpart[k];
        float sx = v[k].x * v[k].x, sy = v[k].y * v[k].y;
        float sz = v[k].z * v[k].z, sw = v[k].w * v[k].w;
        w2m[c4 + 0][o] = sx * inv_r;  w2a[c4 + 0][o] = sx * inv_s22;
        w2m[c4 + 1][o] = sy * inv_r;  w2a[c4 + 1][o] = sy * inv_s22;
        w2m[c4 + 2][o] = sz * inv_r;  w2a[c4 + 2][o] = sz * inv_s22;
        w2m[c4 + 3][o] = sw * inv_r;  w2a[c4 + 3][o] = sw * inv_s22;
    }
    __syncthreads();

    const int l0 = (tid & 15) * 4;
    const int o0 = (tid >> 4) * 4;

    float4 accm[4], acca[4];
    #pragma unroll
    for (int oi = 0; oi < 4; ++oi) {
        accm[oi].x = accm[oi].y = accm[oi].z = accm[oi].w = 0.f;
        acca[oi].x = acca[oi].y = acca[oi].z = acca[oi].w = 0.f;
    }

    const float* m1p = m1 + (size_t)b * NC * NL + lt + l0;
    const float* a1p = a1 + (size_t)b * NC * NL + lt + l0;

    // depth-2 software pipeline over c
    float4 mvA = *(const float4*)(m1p);
    float4 avA = *(const float4*)(a1p);
    float4 mvB = *(const float4*)(m1p + NL);
    float4 avB = *(const float4*)(a1p + NL);

    #pragma unroll 2
    for (int c = 0; c < 62; ++c) {
        float4 mvN = *(const float4*)(m1p + (c + 2) * NL);
        float4 avN = *(const float4*)(a1p + (c + 2) * NL);
        float4 wm_ = *(const float4*)&w2m[c][o0];
        float4 wa_ = *(const float4*)&w2a[c][o0];
        FMA_STEP(mvA, avA, wm_, wa_);
        mvA = mvB; avA = avB;
        mvB = mvN; avB = avN;
    }
    {
        float4 wm_ = *(const float4*)&w2m[62][o0];
        float4 wa_ = *(const float4*)&w2a[62][o0];
        FMA_STEP(mvA, avA, wm_, wa_);
    }
    {
        float4 wm_ = *(const float4*)&w2m[63][o0];
        float4 wa_ = *(const float4*)&w2a[63][o0];
        FMA_STEP(mvB, avB, wm_, wa_);
    }

    #pragma unroll
    for (int oi = 0; oi < 4; ++oi) {
        const int o = o0 + oi;
        float4 mg, oc, os;
        mg.x = __expf(accm[oi].x); mg.y = __expf(accm[oi].y);
        mg.z = __expf(accm[oi].z); mg.w = __expf(accm[oi].w);
        oc.x = mg.x * __cosf(acca[oi].x); os.x = mg.x * __sinf(acca[oi].x);
        oc.y = mg.y * __cosf(acca[oi].y); os.y = mg.y * __sinf(acca[oi].y);
        oc.z = mg.z * __cosf(acca[oi].z); os.z = mg.z * __sinf(acca[oi].z);
        oc.w = mg.w * __cosf(acca[oi].w); os.w = mg.w * __sinf(acca[oi].w);
        size_t gi = ((size_t)(b * 2) * NCOUT + o) * NL + lt + l0;
        *(float4*)&out[gi] = oc;
        *(float4*)&out[gi + (size_t)NCOUT * NL] = os;
    }
}

extern "C" void kernel_launch(void* const* d_in, const int* in_sizes, int n_in,
                              void* d_out, int out_size, void* d_ws, size_t ws_size,
                              hipStream_t stream) {
    const float* x_mag = (const float*)d_in[0];
    const float* x_ang = (const float*)d_in[1];
    const float* w_mag = (const float*)d_in[2];
    const float* w_ang = (const float*)d_in[3];
    const float* w1    = (const float*)d_in[4];
    const float* w2    = (const float*)d_in[5];
    float* out = (float*)d_out;
    float* ws  = (float*)d_ws;

    float* m1 = ws + OFF_M1;
    float* a1 = ws + OFF_A1;

    stageA_kernel<<<NB * NC, 256, 0, stream>>>(x_mag, x_ang, w_mag, w_ang, w1, m1, a1);
    stageB_kernel<<<NB * 64, 256, 0, stream>>>(m1, a1, w2, out);
}